// Round 1
// baseline (3743.069 us; speedup 1.0000x reference)
//
#include <hip/hip_runtime.h>

#define NPTS 131072
#define DIM 256
#define NK 128
#define NITER 10

// ---------------------------------------------------------------------------
// x2[i] = sum_d x[i][d]^2   (16 threads per point, sequential-ish order)
// ---------------------------------------------------------------------------
__global__ void x2_kernel(const float* __restrict__ x, float* __restrict__ x2) {
  int tid = threadIdx.x;
  int p = blockIdx.x * 16 + (tid >> 4);
  int part = tid & 15;
  const float4* xr = (const float4*)(x + (size_t)p * DIM);
  float s = 0.f;
#pragma unroll
  for (int j = 0; j < 4; ++j) {
    float4 v = xr[part * 4 + j];
    s += v.x * v.x;
    s += v.y * v.y;
    s += v.z * v.z;
    s += v.w * v.w;
  }
#pragma unroll
  for (int m = 8; m >= 1; m >>= 1) s += __shfl_xor(s, m, 16);
  if (part == 0) x2[p] = s;
}

// ---------------------------------------------------------------------------
// c2[k] = sum_d c[k][d]^2   (one wave per cluster)
// ---------------------------------------------------------------------------
__global__ void c2_kernel(const float* __restrict__ c, float* __restrict__ c2) {
  int k = blockIdx.x, lane = threadIdx.x;
  float4 v = ((const float4*)(c + (size_t)k * DIM))[lane];
  float s = v.x * v.x + v.y * v.y + v.z * v.z + v.w * v.w;
#pragma unroll
  for (int m = 32; m >= 1; m >>= 1) s += __shfl_xor(s, m, 64);
  if (lane == 0) c2[k] = s;
}

// ---------------------------------------------------------------------------
// Assignment: per block 64 points x 128 clusters, GEMM-tiled.
// dist = (x2 - 2*dot) + c2 computed exactly in reference association.
// ---------------------------------------------------------------------------
__global__ void assign_kernel(const float* __restrict__ x, const float* __restrict__ c,
                              const float* __restrict__ x2, const float* __restrict__ c2,
                              int* __restrict__ assign_out) {
  __shared__ float4 xs4[64 * 4];   // [p][d4 ^ swz]
  __shared__ float4 cs4[128 * 4];  // [k][d4 ^ swz]
  __shared__ float redv[64][17];
  __shared__ int redk[64][17];

  int tid = threadIdx.x;
  int tx = tid & 15;  // point group  (p = tx*4+pp)
  int ty = tid >> 4;  // cluster group (k = ty*8+kk)
  int row0 = blockIdx.x * 64;

  float acc[4][8];
#pragma unroll
  for (int a = 0; a < 4; ++a)
#pragma unroll
    for (int b = 0; b < 8; ++b) acc[a][b] = 0.f;

  for (int ck = 0; ck < 16; ++ck) {  // 16 chunks of 16 dims
    // stage x tile: 256 float4s, one per thread
    {
      int p = tid >> 2, d4 = tid & 3;
      float4 v = *(const float4*)(x + (size_t)(row0 + p) * DIM + ck * 16 + d4 * 4);
      xs4[p * 4 + (d4 ^ ((p >> 2) & 3))] = v;
    }
    // stage c tile: 512 float4s, two per thread
#pragma unroll
    for (int r = 0; r < 2; ++r) {
      int idx = tid + r * 256;
      int kk = idx >> 2, dd = idx & 3;
      float4 v = *(const float4*)(c + (size_t)kk * DIM + ck * 16 + dd * 4);
      cs4[kk * 4 + (dd ^ ((kk >> 3) & 3))] = v;
    }
    __syncthreads();
#pragma unroll
    for (int d4 = 0; d4 < 4; ++d4) {
      float4 xr[4], cr[8];
#pragma unroll
      for (int pp = 0; pp < 4; ++pp) xr[pp] = xs4[(tx * 4 + pp) * 4 + (d4 ^ (tx & 3))];
#pragma unroll
      for (int kk = 0; kk < 8; ++kk) cr[kk] = cs4[(ty * 8 + kk) * 4 + (d4 ^ (ty & 3))];
#pragma unroll
      for (int pp = 0; pp < 4; ++pp)
#pragma unroll
        for (int kk = 0; kk < 8; ++kk) {
          acc[pp][kk] = fmaf(xr[pp].x, cr[kk].x, acc[pp][kk]);
          acc[pp][kk] = fmaf(xr[pp].y, cr[kk].y, acc[pp][kk]);
          acc[pp][kk] = fmaf(xr[pp].z, cr[kk].z, acc[pp][kk]);
          acc[pp][kk] = fmaf(xr[pp].w, cr[kk].w, acc[pp][kk]);
        }
    }
    __syncthreads();
  }

  // epilogue: dist + local argmin over this thread's 8 clusters
  float x2p[4];
#pragma unroll
  for (int pp = 0; pp < 4; ++pp) x2p[pp] = x2[row0 + tx * 4 + pp];

  float bestv[4];
  int bestk[4];
#pragma unroll
  for (int pp = 0; pp < 4; ++pp) { bestv[pp] = 3.4e38f; bestk[pp] = 0; }
#pragma unroll
  for (int kk = 0; kk < 8; ++kk) {
    float c2k = c2[ty * 8 + kk];
#pragma unroll
    for (int pp = 0; pp < 4; ++pp) {
      float d = fmaf(-2.f, acc[pp][kk], x2p[pp]) + c2k;
      if (d < bestv[pp]) { bestv[pp] = d; bestk[pp] = ty * 8 + kk; }
    }
  }
#pragma unroll
  for (int pp = 0; pp < 4; ++pp) {
    redv[tx * 4 + pp][ty] = bestv[pp];
    redk[tx * 4 + pp][ty] = bestk[pp];
  }
  __syncthreads();
  if (tid < 64) {
    float bv = redv[tid][0];
    int bk = redk[tid][0];
#pragma unroll
    for (int t = 1; t < 16; ++t) {
      float v = redv[tid][t];
      if (v < bv) { bv = v; bk = redk[tid][t]; }  // ty ascending = k ascending: first-min
    }
    assign_out[row0 + tid] = bk;
  }
}

// ---------------------------------------------------------------------------
// Per-chunk histogram (chunk = 1024 points)
// ---------------------------------------------------------------------------
__global__ void hist_kernel(const int* __restrict__ assign_in, int* __restrict__ hist) {
  __shared__ int h[NK];
  int tid = threadIdx.x, b = blockIdx.x;
  if (tid < NK) h[tid] = 0;
  __syncthreads();
#pragma unroll
  for (int r = 0; r < 4; ++r) {
    int a = assign_in[b * 1024 + r * 256 + tid];
    atomicAdd(&h[a], 1);
  }
  __syncthreads();
  if (tid < NK) hist[b * NK + tid] = h[tid];
}

// ---------------------------------------------------------------------------
// Scan: per-cluster exclusive prefix over chunks + cluster bases + counts
// ---------------------------------------------------------------------------
__global__ void scan_kernel(const int* __restrict__ hist, int* __restrict__ base,
                            int* __restrict__ counts, int* __restrict__ cbase) {
  int k = threadIdx.x;  // 128 threads
  int run = 0;
  for (int b = 0; b < 128; ++b) {
    base[b * NK + k] = run;
    run += hist[b * NK + k];
  }
  counts[k] = run;
  __syncthreads();
  if (k == 0) {
    int cb = 0;
    for (int j = 0; j < NK; ++j) {
      cbase[j] = cb;
      cb += counts[j];
    }
  }
  __syncthreads();
  int cbk = cbase[k];
  for (int b = 0; b < 128; ++b) base[b * NK + k] += cbk;
}

// ---------------------------------------------------------------------------
// Stable scatter: perm sorted by (cluster, point index). 1 wave per chunk.
// ---------------------------------------------------------------------------
__global__ void scatter_kernel(const int* __restrict__ assign_in, const int* __restrict__ base,
                               int* __restrict__ perm) {
  __shared__ int cnt[NK];
  int lane = threadIdx.x, b = blockIdx.x;
  cnt[lane] = base[b * NK + lane];
  cnt[lane + 64] = base[b * NK + lane + 64];
  __syncthreads();
  for (int r = 0; r < 16; ++r) {
    int p = b * 1024 + r * 64 + lane;
    int a = assign_in[p];
    unsigned long long mask = ~0ull;
#pragma unroll
    for (int j = 0; j < 7; ++j) {
      unsigned long long bal = __ballot((a >> j) & 1);
      mask &= ((a >> j) & 1) ? bal : ~bal;
    }
    int rank = __popcll(mask & ((1ull << lane) - 1ull));
    int pos = cnt[a] + rank;
    perm[pos] = p;
    __syncthreads();
    if (rank == 0) cnt[a] += (int)__popcll(mask);
    __syncthreads();
  }
}

// ---------------------------------------------------------------------------
// Per-cluster sum in index order -> new centroids + c2. One block per cluster.
// ---------------------------------------------------------------------------
__global__ void sum_kernel(const float* __restrict__ x, const int* __restrict__ perm,
                           const int* __restrict__ counts, const int* __restrict__ cbase,
                           float* __restrict__ c, float* __restrict__ c2) {
  __shared__ float wsum[4];
  int k = blockIdx.x, d = threadIdx.x;
  int cnt = counts[k], off = cbase[k];
  float s = 0.f;
  int j = 0;
  for (; j + 4 <= cnt; j += 4) {
    int p0 = perm[off + j + 0];
    int p1 = perm[off + j + 1];
    int p2 = perm[off + j + 2];
    int p3 = perm[off + j + 3];
    s += x[(size_t)p0 * DIM + d];
    s += x[(size_t)p1 * DIM + d];
    s += x[(size_t)p2 * DIM + d];
    s += x[(size_t)p3 * DIM + d];
  }
  for (; j < cnt; ++j) s += x[(size_t)perm[off + j] * DIM + d];

  float nc;
  if (cnt > 0)
    nc = s / fmaxf((float)cnt, 1.0f);
  else
    nc = c[(size_t)k * DIM + d];
  c[(size_t)k * DIM + d] = nc;

  float s2 = nc * nc;
#pragma unroll
  for (int m = 32; m >= 1; m >>= 1) s2 += __shfl_xor(s2, m, 64);
  if ((threadIdx.x & 63) == 0) wsum[threadIdx.x >> 6] = s2;
  __syncthreads();
  if (threadIdx.x == 0) c2[k] = wsum[0] + wsum[1] + wsum[2] + wsum[3];
}

// ---------------------------------------------------------------------------
extern "C" void kernel_launch(void* const* d_in, const int* in_sizes, int n_in,
                              void* d_out, int out_size, void* d_ws, size_t ws_size,
                              hipStream_t stream) {
  const float* x = (const float*)d_in[0];
  char* ws = (char*)d_ws;

  float* c = (float*)(ws + 0);            // 131072 B
  float* c2 = (float*)(ws + 131072);      // 512 B
  float* x2 = (float*)(ws + 132096);      // 524288 B
  int* assignb = (int*)(ws + 656384);     // 524288 B
  int* hist = (int*)(ws + 1180672);       // 65536 B
  int* base = (int*)(ws + 1246208);       // 65536 B
  int* counts = (int*)(ws + 1311744);     // 512 B
  int* cbase = (int*)(ws + 1312256);      // 512 B
  int* perm = (int*)(ws + 1312768);       // 524288 B -> total ~1.84 MB

  // init centroids = x[:128]
  hipMemcpyAsync(c, x, (size_t)NK * DIM * sizeof(float), hipMemcpyDeviceToDevice, stream);
  x2_kernel<<<NPTS / 16, 256, 0, stream>>>(x, x2);
  c2_kernel<<<NK, 64, 0, stream>>>(c, c2);

  for (int it = 0; it < NITER; ++it) {
    assign_kernel<<<NPTS / 64, 256, 0, stream>>>(x, c, x2, c2, assignb);
    hist_kernel<<<NPTS / 1024, 256, 0, stream>>>(assignb, hist);
    scan_kernel<<<1, 128, 0, stream>>>(hist, base, counts, cbase);
    scatter_kernel<<<NPTS / 1024, 64, 0, stream>>>(assignb, base, perm);
    sum_kernel<<<NK, 256, 0, stream>>>(x, perm, counts, cbase, c, c2);
  }

  // final predictions with final centroids -> int32 labels
  assign_kernel<<<NPTS / 64, 256, 0, stream>>>(x, c, x2, c2, (int*)d_out);
}

// Round 2
// 1875.021 us; speedup vs baseline: 1.9963x; 1.9963x over previous
//
#include <hip/hip_runtime.h>

#define NPTS 131072
#define DIM 256
#define NK 128
#define NITER 10
#define SEG 16

// ---------------------------------------------------------------------------
// x2[i] = sum_d x[i][d]^2   (16 threads per point)
// ---------------------------------------------------------------------------
__global__ void x2_kernel(const float* __restrict__ x, float* __restrict__ x2) {
  int tid = threadIdx.x;
  int p = blockIdx.x * 16 + (tid >> 4);
  int part = tid & 15;
  const float4* xr = (const float4*)(x + (size_t)p * DIM);
  float s = 0.f;
#pragma unroll
  for (int j = 0; j < 4; ++j) {
    float4 v = xr[part * 4 + j];
    s += v.x * v.x;
    s += v.y * v.y;
    s += v.z * v.z;
    s += v.w * v.w;
  }
#pragma unroll
  for (int m = 8; m >= 1; m >>= 1) s += __shfl_xor(s, m, 16);
  if (part == 0) x2[p] = s;
}

// ---------------------------------------------------------------------------
// c2[k] = sum_d c[k][d]^2   (one wave per cluster, init only)
// ---------------------------------------------------------------------------
__global__ void c2_kernel(const float* __restrict__ c, float* __restrict__ c2) {
  int k = blockIdx.x, lane = threadIdx.x;
  float4 v = ((const float4*)(c + (size_t)k * DIM))[lane];
  float s = v.x * v.x + v.y * v.y + v.z * v.z + v.w * v.w;
#pragma unroll
  for (int m = 32; m >= 1; m >>= 1) s += __shfl_xor(s, m, 64);
  if (lane == 0) c2[k] = s;
}

// ---------------------------------------------------------------------------
// Assignment: per block 64 points x 128 clusters, GEMM-tiled.
// dist = (x2 - 2*dot) + c2 computed exactly in reference association.
// ---------------------------------------------------------------------------
__global__ void assign_kernel(const float* __restrict__ x, const float* __restrict__ c,
                              const float* __restrict__ x2, const float* __restrict__ c2,
                              int* __restrict__ assign_out) {
  __shared__ float4 xs4[64 * 4];   // [p][d4 ^ swz]
  __shared__ float4 cs4[128 * 4];  // [k][d4 ^ swz]
  __shared__ float redv[64][17];
  __shared__ int redk[64][17];

  int tid = threadIdx.x;
  int tx = tid & 15;  // point group  (p = tx*4+pp)
  int ty = tid >> 4;  // cluster group (k = ty*8+kk)
  int row0 = blockIdx.x * 64;

  float acc[4][8];
#pragma unroll
  for (int a = 0; a < 4; ++a)
#pragma unroll
    for (int b = 0; b < 8; ++b) acc[a][b] = 0.f;

  for (int ck = 0; ck < 16; ++ck) {  // 16 chunks of 16 dims
    {
      int p = tid >> 2, d4 = tid & 3;
      float4 v = *(const float4*)(x + (size_t)(row0 + p) * DIM + ck * 16 + d4 * 4);
      xs4[p * 4 + (d4 ^ ((p >> 2) & 3))] = v;
    }
#pragma unroll
    for (int r = 0; r < 2; ++r) {
      int idx = tid + r * 256;
      int kk = idx >> 2, dd = idx & 3;
      float4 v = *(const float4*)(c + (size_t)kk * DIM + ck * 16 + dd * 4);
      cs4[kk * 4 + (dd ^ ((kk >> 3) & 3))] = v;
    }
    __syncthreads();
#pragma unroll
    for (int d4 = 0; d4 < 4; ++d4) {
      float4 xr[4], cr[8];
#pragma unroll
      for (int pp = 0; pp < 4; ++pp) xr[pp] = xs4[(tx * 4 + pp) * 4 + (d4 ^ (tx & 3))];
#pragma unroll
      for (int kk = 0; kk < 8; ++kk) cr[kk] = cs4[(ty * 8 + kk) * 4 + (d4 ^ (ty & 3))];
#pragma unroll
      for (int pp = 0; pp < 4; ++pp)
#pragma unroll
        for (int kk = 0; kk < 8; ++kk) {
          acc[pp][kk] = fmaf(xr[pp].x, cr[kk].x, acc[pp][kk]);
          acc[pp][kk] = fmaf(xr[pp].y, cr[kk].y, acc[pp][kk]);
          acc[pp][kk] = fmaf(xr[pp].z, cr[kk].z, acc[pp][kk]);
          acc[pp][kk] = fmaf(xr[pp].w, cr[kk].w, acc[pp][kk]);
        }
    }
    __syncthreads();
  }

  float x2p[4];
#pragma unroll
  for (int pp = 0; pp < 4; ++pp) x2p[pp] = x2[row0 + tx * 4 + pp];

  float bestv[4];
  int bestk[4];
#pragma unroll
  for (int pp = 0; pp < 4; ++pp) { bestv[pp] = 3.4e38f; bestk[pp] = 0; }
#pragma unroll
  for (int kk = 0; kk < 8; ++kk) {
    float c2k = c2[ty * 8 + kk];
#pragma unroll
    for (int pp = 0; pp < 4; ++pp) {
      float d = fmaf(-2.f, acc[pp][kk], x2p[pp]) + c2k;
      if (d < bestv[pp]) { bestv[pp] = d; bestk[pp] = ty * 8 + kk; }
    }
  }
#pragma unroll
  for (int pp = 0; pp < 4; ++pp) {
    redv[tx * 4 + pp][ty] = bestv[pp];
    redk[tx * 4 + pp][ty] = bestk[pp];
  }
  __syncthreads();
  if (tid < 64) {
    float bv = redv[tid][0];
    int bk = redk[tid][0];
#pragma unroll
    for (int t = 1; t < 16; ++t) {
      float v = redv[tid][t];
      if (v < bv) { bv = v; bk = redk[tid][t]; }  // ty ascending: first-min
    }
    assign_out[row0 + tid] = bk;
  }
}

// ---------------------------------------------------------------------------
// Per-chunk histogram (chunk = 1024 points)
// ---------------------------------------------------------------------------
__global__ void hist_kernel(const int* __restrict__ assign_in, int* __restrict__ hist) {
  __shared__ int h[NK];
  int tid = threadIdx.x, b = blockIdx.x;
  if (tid < NK) h[tid] = 0;
  __syncthreads();
#pragma unroll
  for (int r = 0; r < 4; ++r) {
    int a = assign_in[b * 1024 + r * 256 + tid];
    atomicAdd(&h[a], 1);
  }
  __syncthreads();
  if (tid < NK) hist[b * NK + tid] = h[tid];
}

// ---------------------------------------------------------------------------
// Scan: LDS-staged. Per-cluster exclusive prefix over 128 chunks + bases.
// ---------------------------------------------------------------------------
__global__ void scan_kernel(const int* __restrict__ hist, int* __restrict__ base,
                            int* __restrict__ counts, int* __restrict__ cbase) {
  __shared__ int h[128 * NK];  // 64 KB
  int tid = threadIdx.x;       // 256 threads
  for (int i = tid; i < 128 * NK; i += 256) h[i] = hist[i];
  __syncthreads();
  if (tid < NK) {
    int run = 0;
    for (int b = 0; b < 128; ++b) {
      int v = h[b * NK + tid];
      h[b * NK + tid] = run;
      run += v;
    }
    counts[tid] = run;
  }
  __syncthreads();
  if (tid == 0) {
    int cb = 0;
#pragma unroll 4
    for (int j = 0; j < NK; ++j) {
      cbase[j] = cb;
      cb += counts[j];
    }
  }
  __syncthreads();
  if (tid < NK) {
    int cbk = cbase[tid];
    for (int b = 0; b < 128; ++b) base[b * NK + tid] = h[b * NK + tid] + cbk;
  }
}

// ---------------------------------------------------------------------------
// Stable scatter: perm sorted by (cluster, point index). 1 wave per chunk.
// ---------------------------------------------------------------------------
__global__ void scatter_kernel(const int* __restrict__ assign_in, const int* __restrict__ base,
                               int* __restrict__ perm) {
  __shared__ int cnt[NK];
  int lane = threadIdx.x, b = blockIdx.x;
  cnt[lane] = base[b * NK + lane];
  cnt[lane + 64] = base[b * NK + lane + 64];
  __syncthreads();
  for (int r = 0; r < 16; ++r) {
    int p = b * 1024 + r * 64 + lane;
    int a = assign_in[p];
    unsigned long long mask = ~0ull;
#pragma unroll
    for (int j = 0; j < 7; ++j) {
      unsigned long long bal = __ballot((a >> j) & 1);
      mask &= ((a >> j) & 1) ? bal : ~bal;
    }
    int rank = __popcll(mask & ((1ull << lane) - 1ull));
    int pos = cnt[a] + rank;
    perm[pos] = p;
    __syncthreads();
    if (rank == 0) cnt[a] += (int)__popcll(mask);
    __syncthreads();
  }
}

// ---------------------------------------------------------------------------
// Segmented per-cluster sum: grid (NK, SEG). Each block sums a fixed
// position-range of cluster k's members (deterministic partition).
// ---------------------------------------------------------------------------
__global__ void seg_sum_kernel(const float* __restrict__ x, const int* __restrict__ perm,
                               const int* __restrict__ counts, const int* __restrict__ cbase,
                               float* __restrict__ partial) {
  int k = blockIdx.x, s = blockIdx.y, d = threadIdx.x;
  int cnt = counts[k], off = cbase[k];
  int j0 = (int)(((long long)cnt * s) / SEG);
  int j1 = (int)(((long long)cnt * (s + 1)) / SEG);
  float sum = 0.f;
  int j = j0;
  for (; j + 4 <= j1; j += 4) {
    int p0 = perm[off + j + 0];
    int p1 = perm[off + j + 1];
    int p2 = perm[off + j + 2];
    int p3 = perm[off + j + 3];
    sum += x[(size_t)p0 * DIM + d];
    sum += x[(size_t)p1 * DIM + d];
    sum += x[(size_t)p2 * DIM + d];
    sum += x[(size_t)p3 * DIM + d];
  }
  for (; j < j1; ++j) sum += x[(size_t)perm[off + j] * DIM + d];
  partial[((size_t)k * SEG + s) * DIM + d] = sum;
}

// ---------------------------------------------------------------------------
// Reduce partials in fixed segment order -> new centroids + c2.
// ---------------------------------------------------------------------------
__global__ void reduce_kernel(const float* __restrict__ partial, const int* __restrict__ counts,
                              float* __restrict__ c, float* __restrict__ c2) {
  __shared__ float wsum[4];
  int k = blockIdx.x, d = threadIdx.x;
  int cnt = counts[k];
  float s = 0.f;
#pragma unroll
  for (int t = 0; t < SEG; ++t) s += partial[((size_t)k * SEG + t) * DIM + d];

  float nc;
  if (cnt > 0)
    nc = s / fmaxf((float)cnt, 1.0f);
  else
    nc = c[(size_t)k * DIM + d];
  c[(size_t)k * DIM + d] = nc;

  float s2 = nc * nc;
#pragma unroll
  for (int m = 32; m >= 1; m >>= 1) s2 += __shfl_xor(s2, m, 64);
  if ((threadIdx.x & 63) == 0) wsum[threadIdx.x >> 6] = s2;
  __syncthreads();
  if (threadIdx.x == 0) c2[k] = wsum[0] + wsum[1] + wsum[2] + wsum[3];
}

// ---------------------------------------------------------------------------
extern "C" void kernel_launch(void* const* d_in, const int* in_sizes, int n_in,
                              void* d_out, int out_size, void* d_ws, size_t ws_size,
                              hipStream_t stream) {
  const float* x = (const float*)d_in[0];
  char* ws = (char*)d_ws;

  float* c = (float*)(ws + 0);             // 131072 B
  float* c2 = (float*)(ws + 131072);       // 512 B
  float* x2 = (float*)(ws + 132096);       // 524288 B
  int* assignb = (int*)(ws + 656384);      // 524288 B
  int* hist = (int*)(ws + 1180672);        // 65536 B
  int* base = (int*)(ws + 1246208);        // 65536 B
  int* counts = (int*)(ws + 1311744);      // 512 B
  int* cbase = (int*)(ws + 1312256);       // 512 B
  int* perm = (int*)(ws + 1312768);        // 524288 B
  float* partial = (float*)(ws + 1837056); // 2097152 B -> total ~3.93 MB

  hipMemcpyAsync(c, x, (size_t)NK * DIM * sizeof(float), hipMemcpyDeviceToDevice, stream);
  x2_kernel<<<NPTS / 16, 256, 0, stream>>>(x, x2);
  c2_kernel<<<NK, 64, 0, stream>>>(c, c2);

  for (int it = 0; it < NITER; ++it) {
    assign_kernel<<<NPTS / 64, 256, 0, stream>>>(x, c, x2, c2, assignb);
    hist_kernel<<<NPTS / 1024, 256, 0, stream>>>(assignb, hist);
    scan_kernel<<<1, 256, 0, stream>>>(hist, base, counts, cbase);
    scatter_kernel<<<NPTS / 1024, 64, 0, stream>>>(assignb, base, perm);
    seg_sum_kernel<<<dim3(NK, SEG), 256, 0, stream>>>(x, perm, counts, cbase, partial);
    reduce_kernel<<<NK, 256, 0, stream>>>(partial, counts, c, c2);
  }

  assign_kernel<<<NPTS / 64, 256, 0, stream>>>(x, c, x2, c2, (int*)d_out);
}